// Round 6
// baseline (472.214 us; speedup 1.0000x reference)
//
#include <hip/hip_runtime.h>
#include <stdint.h>

#define NCELL (512 * 512)
#define DIN   136

// output layout (flat f32, concat in return order)
#define OUT_LAT 2097152ull                 // N*8
#define OUT_C   35651584ull                // OUT_LAT + N*128
#define OUT_H   52428800ull                // OUT_C + N*64

// packed-weight offsets in d_ws (bf16 elements)
#define WPRE_OFF  0        // [5][64][32]   = 10240
#define W2_OFF    10240    // [4][256][32]  = 32768
#define WPOST_OFF 43008    // [2][160][32]  = 10240 ; n' 0..7 dyn, 8..31 pad, 32..159 lat
#define WTOTAL    53248

// LDS: one buffer, 64 rows x 400B = 25600B.
// 400B = 100 dwords; 100 mod 32 = 4 -> 16-row b128 frag reads are 2-way (free).
// row layout: [0..271] X cols 0..135 (GEMM1); [272..399] h_prev.
// after GEMM1 sync: [0..127] pre. LSTM writes hn -> [128..255] (dead X cols 64..127).
#define ROWB  400
#define HOFF  272
#define HNOFF 128

#define TPB 4              // tiles (of 64 cells) per persistent block

typedef __bf16 bf16x8 __attribute__((ext_vector_type(8)));
typedef float  f32x4  __attribute__((ext_vector_type(4)));

__device__ __forceinline__ unsigned short f2bf(float f) {
    unsigned int u = __float_as_uint(f);
    u += 0x7FFF + ((u >> 16) & 1);          // round-to-nearest-even
    return (unsigned short)(u >> 16);
}
__device__ __forceinline__ int pack2(float a, float b) {
    return (int)f2bf(a) | ((int)f2bf(b) << 16);
}
__device__ __forceinline__ float fast_sigmoid(float x) {
    return __builtin_amdgcn_rcpf(1.f + __expf(-x));
}
__device__ __forceinline__ float fast_tanh(float x) {
    float e = __expf(2.f * x);              // inf-safe: rcp(inf)=0 -> 1; e->0 -> -1
    return 1.f - 2.f * __builtin_amdgcn_rcpf(e + 1.f);
}
__device__ __forceinline__ float bf2f_lo(int u) {
    return __uint_as_float((unsigned)u << 16);
}
__device__ __forceinline__ float bf2f_hi(int u) {
    return __uint_as_float((unsigned)u & 0xffff0000u);
}

// Repack weights to bf16, MFMA-B-fragment-friendly: [K/32][Ncol][32]
__global__ void prep_weights(const float* __restrict__ Wpre,
                             const float* __restrict__ Wih,
                             const float* __restrict__ Whh,
                             const float* __restrict__ Wpost,
                             unsigned short* __restrict__ ws) {
    int i = blockIdx.x * 256 + threadIdx.x;
    if (i < 10240) {                                   // Wpre' : K 136->160 pad, N=64
        int k = i & 31, n = (i >> 5) & 63, s = i >> 11;
        int K = s * 32 + k;
        ws[i] = (K < DIN) ? f2bf(Wpre[K * 64 + n]) : (unsigned short)0;
    } else if (i < 43008) {                            // W2'   : K=128 (ih||hh), N=256
        int j = i - 10240;
        int k = j & 31, n = (j >> 5) & 255, s = j >> 13;
        int K = s * 32 + k;
        float v = (K < 64) ? Wih[K * 256 + n] : Whh[(K - 64) * 256 + n];
        ws[i] = f2bf(v);
    } else if (i < WTOTAL) {                           // Wpost2: [2][160][32], line-aligned
        int j = i - 43008;
        int k = j & 31;
        int t2 = j >> 5;            // 0..319
        int n = t2 % 160;
        int s = t2 / 160;
        int K = s * 32 + k;         // 0..63
        float v = 0.f;
        if (n < 8)        v = Wpost[K * DIN + n];          // dyn cols
        else if (n >= 32) v = Wpost[K * DIN + (n - 24)];   // lat cols 0..127
        ws[i] = f2bf(v);
    }
}

// Persistent cooperative kernel: 1024 blocks (exactly 4/CU), each block
// processes 4 consecutive 64-cell tiles with cross-tile register prefetch
// (next tile's gather/dyn/h loads issued mid-current-tile).
__global__ __launch_bounds__(256, 4) void knet_fused(
    const float* __restrict__ dyn_in,
    const float* __restrict__ lat_prev,
    const float* __restrict__ lstm_c,
    const float* __restrict__ lstm_h,
    const int*   __restrict__ coming_from,
    const unsigned short* __restrict__ wsp,
    const float* __restrict__ b_pre,
    const float* __restrict__ b_lstm,
    const float* __restrict__ b_post,
    float* __restrict__ out) {
    __shared__ __align__(16) char Ls[64 * ROWB];

    const int t    = threadIdx.x;
    const int lane = t & 63;
    const int w    = t >> 6;     // wave id = N-tile owner
    const int lr   = lane & 15;
    const int lg   = lane >> 4;

    // gather geometry: thread handles (row gra, dir gd) and (row grb, dir gd)
    const int gra = t >> 3, grb = gra + 32, gd = t & 7;
    const int hr = t >> 2, hq = t & 3;     // h staging: 16 floats @ row hr
    const int dc2 = (t & 3) * 2;           // dyn staging: 2 floats @ row hr

    const unsigned short* wpre_p  = wsp + WPRE_OFF;
    const unsigned short* w2_p    = wsp + W2_OFF;
    const unsigned short* wpost_p = wsp + WPOST_OFF;

    // tile-invariant biases
    const int   hid = w * 16 + lr;
    const float bp   = b_pre[hid];
    const float bi   = b_lstm[hid],       bg = b_lstm[128 + hid];
    const float bf_  = b_lstm[64 + hid],  bo = b_lstm[192 + hid];
    const float bpL0 = b_post[8 + 32 * w + lr];
    const float bpL1 = b_post[24 + 32 * w + lr];
    const float bpd  = b_post[lr & 7];    // used only when w==0 && lr<8

    const int base = blockIdx.x * (64 * TPB);

    // ---------------- prologue: prefetch tile 0 ----------------
    int ns_a = coming_from[(size_t)gd * NCELL + base + gra];
    int ns_b = coming_from[(size_t)gd * NCELL + base + grb];
    float4 pa0, pa1, pa2, pa3, pb0, pb1, pb2, pb3, ph0, ph1, ph2, ph3;
    float2 pdyn;
    {
        const float4* lpA = (const float4*)(lat_prev + (size_t)ns_a * 128 + gd * 16);
        pa0 = lpA[0]; pa1 = lpA[1]; pa2 = lpA[2]; pa3 = lpA[3];
        const float4* lpB = (const float4*)(lat_prev + (size_t)ns_b * 128 + gd * 16);
        pb0 = lpB[0]; pb1 = lpB[1]; pb2 = lpB[2]; pb3 = lpB[3];
        pdyn = *(const float2*)(dyn_in + (size_t)(base + hr) * 8 + dc2);
        const float4* hp = (const float4*)(lstm_h + (size_t)(base + hr) * 64 + hq * 16);
        ph0 = hp[0]; ph1 = hp[1]; ph2 = hp[2]; ph3 = hp[3];
    }

    for (int tile = 0; tile < TPB; ++tile) {
        const int p0 = base + tile * 64;

        // ---------------- stage prefetched regs -> LDS ----------------
        {
            char* dA = Ls + gra * ROWB + 16 + 32 * gd;
            *(int4*)dA = int4{pack2(pa0.x, pa0.y), pack2(pa0.z, pa0.w),
                              pack2(pa1.x, pa1.y), pack2(pa1.z, pa1.w)};
            *(int4*)(dA + 16) = int4{pack2(pa2.x, pa2.y), pack2(pa2.z, pa2.w),
                                     pack2(pa3.x, pa3.y), pack2(pa3.z, pa3.w)};
            char* dB = Ls + grb * ROWB + 16 + 32 * gd;
            *(int4*)dB = int4{pack2(pb0.x, pb0.y), pack2(pb0.z, pb0.w),
                              pack2(pb1.x, pb1.y), pack2(pb1.z, pb1.w)};
            *(int4*)(dB + 16) = int4{pack2(pb2.x, pb2.y), pack2(pb2.z, pb2.w),
                                     pack2(pb3.x, pb3.y), pack2(pb3.z, pb3.w)};
            *(int*)(Ls + hr * ROWB + dc2 * 2) = pack2(pdyn.x, pdyn.y);
            char* dH = Ls + hr * ROWB + HOFF + hq * 32;
            *(int4*)dH = int4{pack2(ph0.x, ph0.y), pack2(ph0.z, ph0.w),
                              pack2(ph1.x, ph1.y), pack2(ph1.z, ph1.w)};
            *(int4*)(dH + 16) = int4{pack2(ph2.x, ph2.y), pack2(ph2.z, ph2.w),
                                     pack2(ph3.x, ph3.y), pack2(ph3.z, ph3.w)};
        }
        // issue next tile's gather indices (resolve during GEMM1/GEMM2-A)
        if (tile + 1 < TPB) {
            ns_a = coming_from[(size_t)gd * NCELL + p0 + 64 + gra];
            ns_b = coming_from[(size_t)gd * NCELL + p0 + 64 + grb];
        }
        __syncthreads();   // X + h_prev ready

        // ---------------- GEMM1: X[64x(136->160)] @ Wpre'[160x64] -> pre ----------
        {
            f32x4 acc1[4];
#pragma unroll
            for (int m = 0; m < 4; ++m) acc1[m] = (f32x4){0.f, 0.f, 0.f, 0.f};
#pragma unroll
            for (int s = 0; s < 4; ++s) {
                bf16x8 b = *(const bf16x8*)(wpre_p + ((s * 64 + hid) * 32 + lg * 8));
#pragma unroll
                for (int m = 0; m < 4; ++m) {
                    bf16x8 a = *(const bf16x8*)(Ls + (m * 16 + lr) * ROWB + s * 64 + lg * 16);
                    acc1[m] = __builtin_amdgcn_mfma_f32_16x16x32_bf16(a, b, acc1[m], 0, 0, 0);
                }
            }
            {   // s=4: A cols 128..159 = {cols 128..135 (lg==0), zeros}
                bf16x8 b4 = *(const bf16x8*)(wpre_p + ((4 * 64 + hid) * 32 + lg * 8));
#pragma unroll
                for (int m = 0; m < 4; ++m) {
                    bf16x8 a4 = {};
                    if (lg == 0)
                        a4 = *(const bf16x8*)(Ls + (m * 16 + lr) * ROWB + 256);
                    acc1[m] = __builtin_amdgcn_mfma_f32_16x16x32_bf16(a4, b4, acc1[m], 0, 0, 0);
                }
            }
            int colb = hid * 2;
#pragma unroll
            for (int m = 0; m < 4; ++m)
#pragma unroll
                for (int rr = 0; rr < 4; ++rr) {
                    int row = m * 16 + lg * 4 + rr;
                    float pv = fast_tanh(acc1[m][rr] + bp);
                    *(unsigned short*)(Ls + row * ROWB + colb) = f2bf(pv);
                }
        }
        __syncthreads();   // pre visible; X reads retired

        // ---------------- GEMM2: [pre||h][64x128] @ W2'[128x256], 2 passes + LSTM --
        {
            // ---- pass A: i (tile w), g (tile w+8) ----
            f32x4 acc[4][2];
#pragma unroll
            for (int m = 0; m < 4; ++m)
#pragma unroll
                for (int j = 0; j < 2; ++j) acc[m][j] = (f32x4){0.f, 0.f, 0.f, 0.f};
#pragma unroll
            for (int s = 0; s < 4; ++s) {
                const int abyte = (s < 2) ? (s * 64 + lg * 16)
                                          : (HOFF + (s - 2) * 64 + lg * 16);
                bf16x8 b0 = *(const bf16x8*)(w2_p + ((s * 256 + (w)     * 16 + lr) * 32 + lg * 8));
                bf16x8 b1 = *(const bf16x8*)(w2_p + ((s * 256 + (w + 8) * 16 + lr) * 32 + lg * 8));
#pragma unroll
                for (int m = 0; m < 4; ++m) {
                    bf16x8 a = *(const bf16x8*)(Ls + (m * 16 + lr) * ROWB + abyte);
                    acc[m][0] = __builtin_amdgcn_mfma_f32_16x16x32_bf16(a, b0, acc[m][0], 0, 0, 0);
                    acc[m][1] = __builtin_amdgcn_mfma_f32_16x16x32_bf16(a, b1, acc[m][1], 0, 0, 0);
                }
            }
            // ig = sigmoid(i)*tanh(g), packed bf16 (8 regs)
            int igp[8];
#pragma unroll
            for (int m = 0; m < 4; ++m)
#pragma unroll
                for (int pp = 0; pp < 2; ++pp) {
                    float g0 = fast_sigmoid(acc[m][0][2 * pp]     + bi) *
                               fast_tanh(acc[m][1][2 * pp]     + bg);
                    float g1 = fast_sigmoid(acc[m][0][2 * pp + 1] + bi) *
                               fast_tanh(acc[m][1][2 * pp + 1] + bg);
                    igp[m * 2 + pp] = pack2(g0, g1);
                }

            // prefetch c_old for this tile (hidden under pass B MFMAs)
            float cpf[16];
#pragma unroll
            for (int m = 0; m < 4; ++m)
#pragma unroll
                for (int rr = 0; rr < 4; ++rr)
                    cpf[m * 4 + rr] =
                        lstm_c[(size_t)(p0 + m * 16 + lg * 4 + rr) * 64 + hid];

            // issue next tile's lat/dyn/h prefetch (lands during passB/G3/stores)
            if (tile + 1 < TPB) {
                const int np0 = p0 + 64;
                const float4* lpA = (const float4*)(lat_prev + (size_t)ns_a * 128 + gd * 16);
                pa0 = lpA[0]; pa1 = lpA[1]; pa2 = lpA[2]; pa3 = lpA[3];
                const float4* lpB = (const float4*)(lat_prev + (size_t)ns_b * 128 + gd * 16);
                pb0 = lpB[0]; pb1 = lpB[1]; pb2 = lpB[2]; pb3 = lpB[3];
                pdyn = *(const float2*)(dyn_in + (size_t)(np0 + hr) * 8 + dc2);
                const float4* hp = (const float4*)(lstm_h + (size_t)(np0 + hr) * 64 + hq * 16);
                ph0 = hp[0]; ph1 = hp[1]; ph2 = hp[2]; ph3 = hp[3];
            }

            // ---- pass B: f (tile w+4), o (tile w+12) ----
#pragma unroll
            for (int m = 0; m < 4; ++m)
#pragma unroll
                for (int j = 0; j < 2; ++j) acc[m][j] = (f32x4){0.f, 0.f, 0.f, 0.f};
#pragma unroll
            for (int s = 0; s < 4; ++s) {
                const int abyte = (s < 2) ? (s * 64 + lg * 16)
                                          : (HOFF + (s - 2) * 64 + lg * 16);
                bf16x8 b0 = *(const bf16x8*)(w2_p + ((s * 256 + (w + 4)  * 16 + lr) * 32 + lg * 8));
                bf16x8 b1 = *(const bf16x8*)(w2_p + ((s * 256 + (w + 12) * 16 + lr) * 32 + lg * 8));
#pragma unroll
                for (int m = 0; m < 4; ++m) {
                    bf16x8 a = *(const bf16x8*)(Ls + (m * 16 + lr) * ROWB + abyte);
                    acc[m][0] = __builtin_amdgcn_mfma_f32_16x16x32_bf16(a, b0, acc[m][0], 0, 0, 0);
                    acc[m][1] = __builtin_amdgcn_mfma_f32_16x16x32_bf16(a, b1, acc[m][1], 0, 0, 0);
                }
            }
            // ---- LSTM pointwise: c -> global (f32), hn -> LDS bytes 128..255 ----
#pragma unroll
            for (int m = 0; m < 4; ++m)
#pragma unroll
                for (int rr = 0; rr < 4; ++rr) {
                    int row = m * 16 + lg * 4 + rr;
                    size_t cell = (size_t)(p0 + row);
                    float fv = fast_sigmoid(acc[m][0][rr] + bf_);
                    float ov = fast_sigmoid(acc[m][1][rr] + bo);
                    float igv = (rr & 1) ? bf2f_hi(igp[m * 2 + (rr >> 1)])
                                         : bf2f_lo(igp[m * 2 + (rr >> 1)]);
                    float cn = fv * cpf[m * 4 + rr] + igv;
                    float hn = ov * fast_tanh(cn);
                    out[OUT_C + cell * 64 + hid] = cn;
                    *(unsigned short*)(Ls + row * ROWB + HNOFF + 2 * hid) = f2bf(hn);
                }
        }
        __syncthreads();   // hn visible

        // ---------------- cooperative full-line h stores ----------------
        {
            const char* rp = Ls + hr * ROWB + HNOFF + hq * 32;
            int4 h0 = *(const int4*)rp;
            int4 h1 = *(const int4*)(rp + 16);
            float* op = out + OUT_H + (size_t)(p0 + hr) * 64 + hq * 16;
            *(float4*)(op)      = float4{bf2f_lo(h0.x), bf2f_hi(h0.x), bf2f_lo(h0.y), bf2f_hi(h0.y)};
            *(float4*)(op + 4)  = float4{bf2f_lo(h0.z), bf2f_hi(h0.z), bf2f_lo(h0.w), bf2f_hi(h0.w)};
            *(float4*)(op + 8)  = float4{bf2f_lo(h1.x), bf2f_hi(h1.x), bf2f_lo(h1.y), bf2f_hi(h1.y)};
            *(float4*)(op + 12) = float4{bf2f_lo(h1.z), bf2f_hi(h1.z), bf2f_lo(h1.w), bf2f_hi(h1.w)};
        }

        // ---------------- GEMM3: hn[64x64] @ Wpost2'[64x160] -> lat (+dyn on w0) ----
        {
            f32x4 acc3[4][2];
#pragma unroll
            for (int m = 0; m < 4; ++m)
#pragma unroll
                for (int jj = 0; jj < 2; ++jj) acc3[m][jj] = (f32x4){0.f, 0.f, 0.f, 0.f};
#pragma unroll
            for (int s = 0; s < 2; ++s) {
                bf16x8 a[4];
#pragma unroll
                for (int m = 0; m < 4; ++m)
                    a[m] = *(const bf16x8*)(Ls + (m * 16 + lr) * ROWB + HNOFF +
                                            s * 64 + lg * 16);
#pragma unroll
                for (int jj = 0; jj < 2; ++jj) {
                    int n = 2 * w + 2 + jj;
                    bf16x8 b =
                        *(const bf16x8*)(wpost_p + ((s * 160 + n * 16 + lr) * 32 + lg * 8));
#pragma unroll
                    for (int m = 0; m < 4; ++m)
                        acc3[m][jj] = __builtin_amdgcn_mfma_f32_16x16x32_bf16(a[m], b,
                                                                              acc3[m][jj],
                                                                              0, 0, 0);
                }
            }
#pragma unroll
            for (int jj = 0; jj < 2; ++jj) {
                int L = 32 * w + 16 * jj + lr;            // lat col 0..127
                float bpv = (jj == 0) ? bpL0 : bpL1;
#pragma unroll
                for (int m = 0; m < 4; ++m)
#pragma unroll
                    for (int rr = 0; rr < 4; ++rr) {
                        int row = m * 16 + lg * 4 + rr;
                        out[OUT_LAT + (size_t)(p0 + row) * 128 + L] =
                            fast_tanh(acc3[m][jj][rr] + bpv);
                    }
            }
            if (w == 0) {                                 // dyn tile (wave-uniform)
                f32x4 accD[4];
#pragma unroll
                for (int m = 0; m < 4; ++m) accD[m] = (f32x4){0.f, 0.f, 0.f, 0.f};
#pragma unroll
                for (int s = 0; s < 2; ++s) {
                    bf16x8 b = *(const bf16x8*)(wpost_p + ((s * 160 + lr) * 32 + lg * 8));
#pragma unroll
                    for (int m = 0; m < 4; ++m) {
                        bf16x8 a = *(const bf16x8*)(Ls + (m * 16 + lr) * ROWB + HNOFF +
                                                    s * 64 + lg * 16);
                        accD[m] = __builtin_amdgcn_mfma_f32_16x16x32_bf16(a, b, accD[m],
                                                                          0, 0, 0);
                    }
                }
                if (lr < 8) {
#pragma unroll
                    for (int m = 0; m < 4; ++m)
#pragma unroll
                        for (int rr = 0; rr < 4; ++rr) {
                            int row = m * 16 + lg * 4 + rr;
                            out[(size_t)(p0 + row) * 8 + lr] =
                                fast_tanh(accD[m][rr] + bpd);
                        }
                }
            }
        }
        __syncthreads();   // all LDS reads retired before next tile's staging writes
    }
}

extern "C" void kernel_launch(void* const* d_in, const int* in_sizes, int n_in,
                              void* d_out, int out_size, void* d_ws, size_t ws_size,
                              hipStream_t stream) {
    const float* dyn_in      = (const float*)d_in[0];
    const float* lat_prev    = (const float*)d_in[1];
    const float* lstm_c      = (const float*)d_in[2];
    const float* lstm_h      = (const float*)d_in[3];
    const int*   coming_from = (const int*)d_in[5];
    const float* W_pre  = (const float*)d_in[7];
    const float* b_pre  = (const float*)d_in[8];
    const float* W_ih   = (const float*)d_in[9];
    const float* W_hh   = (const float*)d_in[10];
    const float* b_lstm = (const float*)d_in[11];
    const float* W_post = (const float*)d_in[12];
    const float* b_post = (const float*)d_in[13];
    unsigned short* wsp = (unsigned short*)d_ws;

    prep_weights<<<(WTOTAL + 255) / 256, 256, 0, stream>>>(W_pre, W_ih, W_hh, W_post, wsp);
    knet_fused<<<NCELL / (64 * TPB), 256, 0, stream>>>(dyn_in, lat_prev, lstm_c, lstm_h,
                                                       coming_from, wsp, b_pre, b_lstm,
                                                       b_post, (float*)d_out);
}

// Round 7
// 180.377 us; speedup vs baseline: 2.6179x; 2.6179x over previous
//
#include <hip/hip_runtime.h>
#include <stdint.h>

#define NCELL (512 * 512)
#define DIN   136

// output layout (flat f32, concat in return order)
#define OUT_LAT 2097152ull                 // N*8
#define OUT_C   35651584ull                // OUT_LAT + N*128
#define OUT_H   52428800ull                // OUT_C + N*64

// packed-weight offsets in d_ws (bf16 elements)
#define WPRE_OFF  0        // [5][64][32]   = 10240
#define W2_OFF    10240    // [4][256][32]  = 32768
#define WPOST_OFF 43008    // [2][160][32]  = 10240 ; n' 0..7 dyn, 8..31 pad, 32..159 lat
#define WTOTAL    53248

#define ROWB 336           // LDS bytes per cell-row (21*16; 5r mod 8 spreads bank slots)

typedef __bf16 bf16x8 __attribute__((ext_vector_type(8)));
typedef __bf16 bf16x2 __attribute__((ext_vector_type(2)));
typedef float  f32x4  __attribute__((ext_vector_type(4)));

// Native casts -> compiler emits v_cvt_pk_bf16_f32 (RTNE), ~2.5x fewer VALU ops
// than the manual round-and-shift sequence (catalog m240: let the compiler do it).
__device__ __forceinline__ unsigned short f2bf(float f) {
    __bf16 v = (__bf16)f;
    unsigned short r;
    __builtin_memcpy(&r, &v, 2);
    return r;
}
__device__ __forceinline__ int pack2(float a, float b) {
    bf16x2 v{(__bf16)a, (__bf16)b};
    int r;
    __builtin_memcpy(&r, &v, 4);
    return r;
}
__device__ __forceinline__ float fast_sigmoid(float x) {
    return __builtin_amdgcn_rcpf(1.f + __expf(-x));
}
__device__ __forceinline__ float fast_tanh(float x) {
    float e = __expf(2.f * x);              // inf-safe: rcp(inf)=0 -> 1; e->0 -> -1
    return 1.f - 2.f * __builtin_amdgcn_rcpf(e + 1.f);
}
__device__ __forceinline__ float bf2f_lo(int u) {
    return __uint_as_float((unsigned)u << 16);
}
__device__ __forceinline__ float bf2f_hi(int u) {
    return __uint_as_float((unsigned)u & 0xffff0000u);
}

// Repack weights to bf16, MFMA-B-fragment-friendly: [K/32][Ncol][32]
__global__ void prep_weights(const float* __restrict__ Wpre,
                             const float* __restrict__ Wih,
                             const float* __restrict__ Whh,
                             const float* __restrict__ Wpost,
                             unsigned short* __restrict__ ws) {
    int i = blockIdx.x * 256 + threadIdx.x;
    if (i < 10240) {                                   // Wpre' : K 136->160 pad, N=64
        int k = i & 31, n = (i >> 5) & 63, s = i >> 11;
        int K = s * 32 + k;
        ws[i] = (K < DIN) ? f2bf(Wpre[K * 64 + n]) : (unsigned short)0;
    } else if (i < 43008) {                            // W2'   : K=128 (ih||hh), N=256
        int j = i - 10240;
        int k = j & 31, n = (j >> 5) & 255, s = j >> 13;
        int K = s * 32 + k;
        float v = (K < 64) ? Wih[K * 256 + n] : Whh[(K - 64) * 256 + n];
        ws[i] = f2bf(v);
    } else if (i < WTOTAL) {                           // Wpost2: [2][160][32], line-aligned
        int j = i - 43008;
        int k = j & 31;
        int t2 = j >> 5;            // 0..319
        int n = t2 % 160;
        int s = t2 / 160;
        int K = s * 32 + k;         // 0..63
        float v = 0.f;
        if (n < 8)        v = Wpost[K * DIN + n];          // dyn cols
        else if (n >= 32) v = Wpost[K * DIN + (n - 24)];   // lat cols 0..127
        ws[i] = f2bf(v);
    }
}

// Cooperative fused kernel: block = 256 threads (4 waves) = 64 cells.
// R4 structure (proven cache-optimal schedule: 4096 dispatch-ordered blocks,
// 4 blocks/CU) with native bf16 conversion (v_cvt_pk_bf16_f32).
__global__ __launch_bounds__(256, 4) void knet_fused(
    const float* __restrict__ dyn_in,
    const float* __restrict__ lat_prev,
    const float* __restrict__ lstm_c,
    const float* __restrict__ lstm_h,
    const int*   __restrict__ coming_from,
    const unsigned short* __restrict__ wsp,
    const float* __restrict__ b_pre,
    const float* __restrict__ b_lstm,
    const float* __restrict__ b_post,
    float* __restrict__ out) {
    // Xs: [64][336B] : X bf16 cols 0..159 during GEMM1 (272..319 zero pad).
    //     During LSTM epilogue (Xs dead): hn bf16 -> bytes 0..127 (XOR swz),
    //     cn bf16 -> bytes 128..255 (same swz). Read by GEMM3 + coop stores.
    __shared__ __align__(16) char Xs[64 * ROWB];
    // A2s: [64][128] bf16 (cols 0-63 = pre, 64-127 = h_prev), XOR-swizzled rows
    __shared__ __align__(16) unsigned short A2s[64 * 128];

    const int t  = threadIdx.x;
    const int p0 = blockIdx.x * 64;
    const unsigned short* wpre_p  = wsp + WPRE_OFF;
    const unsigned short* w2_p    = wsp + W2_OFF;
    const unsigned short* wpost_p = wsp + WPOST_OFF;

    // ---------------- phase 0: staging ----------------
    {
        // h_prev -> A2s cols 64..127 (bf16, swizzled). 16 values/thread.
        int r = t >> 2, q = t & 3;
        int sw = (r & 7) << 4;
        const float4* hp = (const float4*)(lstm_h + (size_t)(p0 + r) * 64 + q * 16);
        float4 v0 = hp[0], v1 = hp[1], v2 = hp[2], v3 = hp[3];
        char* rowp = (char*)A2s + r * 256;
        int4 w0{pack2(v0.x, v0.y), pack2(v0.z, v0.w), pack2(v1.x, v1.y), pack2(v1.z, v1.w)};
        int4 w1{pack2(v2.x, v2.y), pack2(v2.z, v2.w), pack2(v3.x, v3.y), pack2(v3.z, v3.w)};
        *(int4*)(rowp + ((128 + 32 * q) ^ sw))      = w0;
        *(int4*)(rowp + ((128 + 32 * q + 16) ^ sw)) = w1;

        // zero pad X cols 136..159 (bytes 272..319)
        if (q < 3) *(int4*)(Xs + r * ROWB + 272 + 16 * q) = int4{0, 0, 0, 0};
    }
    if (t < 128) {  // dyn_in -> X cols 0..7
        int r = t >> 1, c = (t & 1) * 4;
        float4 v = *(const float4*)(dyn_in + (size_t)(p0 + r) * 8 + c);
        int2 wv{pack2(v.x, v.y), pack2(v.z, v.w)};
        *(int2*)(Xs + r * ROWB + c * 2) = wv;
    }
#pragma unroll
    for (int qq = 0; qq < 2; ++qq) {  // lat gather -> X cols 8..135
        int q = t + qq * 256;
        int r = q >> 3, d = q & 7;
        int src = coming_from[(size_t)d * NCELL + p0 + r];
        const float4* lp = (const float4*)(lat_prev + (size_t)src * 128 + d * 16);
        float4 v0 = lp[0], v1 = lp[1], v2 = lp[2], v3 = lp[3];
        char* dst = Xs + r * ROWB + 16 + 32 * d;
        int4 w0{pack2(v0.x, v0.y), pack2(v0.z, v0.w), pack2(v1.x, v1.y), pack2(v1.z, v1.w)};
        int4 w1{pack2(v2.x, v2.y), pack2(v2.z, v2.w), pack2(v3.x, v3.y), pack2(v3.z, v3.w)};
        *(int4*)dst        = w0;
        *(int4*)(dst + 16) = w1;
    }
    __syncthreads();

    const int lane = t & 63;
    const int w    = t >> 6;     // wave id = N-tile owner
    const int lr   = lane & 15;
    const int lg   = lane >> 4;

    // ---------------- GEMM1: X[64x160] @ Wpre'[160x64] -> pre -> A2s cols 0..63
    {
        f32x4 acc1[4];
#pragma unroll
        for (int m = 0; m < 4; ++m) acc1[m] = (f32x4){0.f, 0.f, 0.f, 0.f};
#pragma unroll
        for (int s = 0; s < 5; ++s) {
            bf16x8 b = *(const bf16x8*)(wpre_p + ((s * 64 + w * 16 + lr) * 32 + lg * 8));
#pragma unroll
            for (int m = 0; m < 4; ++m) {
                bf16x8 a = *(const bf16x8*)(Xs + (m * 16 + lr) * ROWB + s * 64 + lg * 16);
                acc1[m] = __builtin_amdgcn_mfma_f32_16x16x32_bf16(a, b, acc1[m], 0, 0, 0);
            }
        }
        float bp = b_pre[w * 16 + lr];
        int colb = (w * 16 + lr) * 2;
#pragma unroll
        for (int m = 0; m < 4; ++m)
#pragma unroll
            for (int rr = 0; rr < 4; ++rr) {
                int row = m * 16 + lg * 4 + rr;
                float pv = fast_tanh(acc1[m][rr] + bp);
                *(unsigned short*)((char*)A2s + row * 256 + (colb ^ ((row & 7) << 4))) =
                    f2bf(pv);
            }
    }
    __syncthreads();   // pre/h visible (also: all GEMM1 X-reads retired)

    // ---------------- GEMM2: [pre||h][64x128] @ W2'[128x256] + LSTM ----------------
    {
        const int hid = w * 16 + lr;
        // prefetch c_old early (hide latency under MFMAs)
        float cpf[16];
#pragma unroll
        for (int m = 0; m < 4; ++m)
#pragma unroll
            for (int rr = 0; rr < 4; ++rr)
                cpf[m * 4 + rr] =
                    lstm_c[(size_t)(p0 + m * 16 + lg * 4 + rr) * 64 + hid];

        f32x4 acc2[4][4];  // [m][j], gate tile n = w + 4*j  (j: 0=i,1=f,2=g,3=o)
#pragma unroll
        for (int m = 0; m < 4; ++m)
#pragma unroll
            for (int j = 0; j < 4; ++j) acc2[m][j] = (f32x4){0.f, 0.f, 0.f, 0.f};
#pragma unroll
        for (int s = 0; s < 4; ++s) {
            bf16x8 a[4];
#pragma unroll
            for (int m = 0; m < 4; ++m) {
                int row = m * 16 + lr;
                int cb  = (s * 32 + lg * 8) * 2;
                a[m] = *(const bf16x8*)((char*)A2s + row * 256 + (cb ^ ((row & 7) << 4)));
            }
#pragma unroll
            for (int j = 0; j < 4; ++j) {
                int n = w + 4 * j;
                bf16x8 b = *(const bf16x8*)(w2_p + ((s * 256 + n * 16 + lr) * 32 + lg * 8));
#pragma unroll
                for (int m = 0; m < 4; ++m)
                    acc2[m][j] =
                        __builtin_amdgcn_mfma_f32_16x16x32_bf16(a[m], b, acc2[m][j], 0, 0, 0);
            }
        }
        // LSTM pointwise: results -> LDS only (coop full-line stores after sync)
        float bi  = b_lstm[hid],       bfv = b_lstm[64 + hid];
        float bg  = b_lstm[128 + hid], bo  = b_lstm[192 + hid];
#pragma unroll
        for (int m = 0; m < 4; ++m)
#pragma unroll
            for (int rr = 0; rr < 4; ++rr) {
                int row = m * 16 + lg * 4 + rr;
                float iv = fast_sigmoid(acc2[m][0][rr] + bi);
                float fv = fast_sigmoid(acc2[m][1][rr] + bfv);
                float gv = fast_tanh(acc2[m][2][rr] + bg);
                float ov = fast_sigmoid(acc2[m][3][rr] + bo);
                float cn = fv * cpf[m * 4 + rr] + iv * gv;
                float hn = ov * fast_tanh(cn);
                int sw = (row & 7) << 4;
                char* rp = Xs + row * ROWB;       // Xs dead since GEMM1
                *(unsigned short*)(rp + ((2 * hid) ^ sw))       = f2bf(hn);
                *(unsigned short*)(rp + 128 + ((2 * hid) ^ sw)) = f2bf(cn);
            }
    }
    __syncthreads();   // hn/cn visible

    // ---------------- cooperative full-line c/h stores ----------------
    {
#pragma unroll
        for (int q = 0; q < 2; ++q) {
            int row = (t >> 3) + q * 32;
            int ch  = t & 7;
            const char* rp = Xs + row * ROWB;
            int off = (ch * 16) ^ ((row & 7) << 4);
            int4 hv = *(const int4*)(rp + off);
            int4 cv = *(const int4*)(rp + 128 + off);
            size_t rb = (size_t)(p0 + row) * 64 + ch * 8;
            float4 a0{bf2f_lo(cv.x), bf2f_hi(cv.x), bf2f_lo(cv.y), bf2f_hi(cv.y)};
            float4 a1{bf2f_lo(cv.z), bf2f_hi(cv.z), bf2f_lo(cv.w), bf2f_hi(cv.w)};
            *(float4*)(out + OUT_C + rb)     = a0;
            *(float4*)(out + OUT_C + rb + 4) = a1;
            float4 b0{bf2f_lo(hv.x), bf2f_hi(hv.x), bf2f_lo(hv.y), bf2f_hi(hv.y)};
            float4 b1{bf2f_lo(hv.z), bf2f_hi(hv.z), bf2f_lo(hv.w), bf2f_hi(hv.w)};
            *(float4*)(out + OUT_H + rb)     = b0;
            *(float4*)(out + OUT_H + rb + 4) = b1;
        }
    }

    // ---------------- GEMM3: hn[64x64] @ Wpost2'[64x160], tanh -> dyn/lat ----------
    // wave w owns tiles {2w+2, 2w+3} = lat 32-col line w of every row (single-writer
    // full lines); wave 0 additionally does the dyn tile (n'=0).
    {
        f32x4 acc3[4][3];
#pragma unroll
        for (int m = 0; m < 4; ++m)
#pragma unroll
            for (int jj = 0; jj < 3; ++jj) acc3[m][jj] = (f32x4){0.f, 0.f, 0.f, 0.f};
#pragma unroll
        for (int s = 0; s < 2; ++s) {
            bf16x8 a[4];
#pragma unroll
            for (int m = 0; m < 4; ++m) {
                int row = m * 16 + lr;
                a[m] = *(const bf16x8*)(Xs + row * ROWB +
                                        ((s * 64 + lg * 16) ^ ((lr & 7) << 4)));
            }
#pragma unroll
            for (int jj = 0; jj < 3; ++jj) {
                if (jj == 0 && w != 0) continue;
                int n = (jj == 0) ? 0 : (2 * w + 1 + jj);
                bf16x8 b =
                    *(const bf16x8*)(wpost_p + ((s * 160 + n * 16 + lr) * 32 + lg * 8));
#pragma unroll
                for (int m = 0; m < 4; ++m)
                    acc3[m][jj] = __builtin_amdgcn_mfma_f32_16x16x32_bf16(a[m], b,
                                                                          acc3[m][jj],
                                                                          0, 0, 0);
            }
        }
        // epilogue: per-lane scalar stores, but every 128B line single-writer now
        if (w == 0 && lr < 8) {                       // dyn tile
            float bpv = b_post[lr];
#pragma unroll
            for (int m = 0; m < 4; ++m)
#pragma unroll
                for (int rr = 0; rr < 4; ++rr) {
                    int row = m * 16 + lg * 4 + rr;
                    out[(size_t)(p0 + row) * 8 + lr] =
                        fast_tanh(acc3[m][0][rr] + bpv);
                }
        }
#pragma unroll
        for (int jj = 1; jj < 3; ++jj) {              // lat tiles (line w)
            int n = 2 * w + 1 + jj;
            int L = n * 16 + lr - 32;                 // lat col 0..127
            float bpv = b_post[L + 8];
#pragma unroll
            for (int m = 0; m < 4; ++m)
#pragma unroll
                for (int rr = 0; rr < 4; ++rr) {
                    int row = m * 16 + lg * 4 + rr;
                    out[OUT_LAT + (size_t)(p0 + row) * 128 + L] =
                        fast_tanh(acc3[m][jj][rr] + bpv);
                }
        }
    }
}

extern "C" void kernel_launch(void* const* d_in, const int* in_sizes, int n_in,
                              void* d_out, int out_size, void* d_ws, size_t ws_size,
                              hipStream_t stream) {
    const float* dyn_in      = (const float*)d_in[0];
    const float* lat_prev    = (const float*)d_in[1];
    const float* lstm_c      = (const float*)d_in[2];
    const float* lstm_h      = (const float*)d_in[3];
    const int*   coming_from = (const int*)d_in[5];
    const float* W_pre  = (const float*)d_in[7];
    const float* b_pre  = (const float*)d_in[8];
    const float* W_ih   = (const float*)d_in[9];
    const float* W_hh   = (const float*)d_in[10];
    const float* b_lstm = (const float*)d_in[11];
    const float* W_post = (const float*)d_in[12];
    const float* b_post = (const float*)d_in[13];
    unsigned short* wsp = (unsigned short*)d_ws;

    prep_weights<<<(WTOTAL + 255) / 256, 256, 0, stream>>>(W_pre, W_ih, W_hh, W_post, wsp);
    knet_fused<<<NCELL / 64, 256, 0, stream>>>(dyn_in, lat_prev, lstm_c, lstm_h, coming_from,
                                               wsp, b_pre, b_lstm, b_post, (float*)d_out);
}